// Round 6
// baseline (109.111 us; speedup 1.0000x reference)
//
#include <hip/hip_runtime.h>

// ResidualBlock2 (AdderNet): two adder-convs + BN + ReLU + residual.
// N=32, C=32, H=W=32, K=3. No multiplies -> no MFMA; pure VALU (2 instr per
// |x-w| contribution; VALU floor ~7.7us/conv, 576 CU-cyc per ci).
// R6: retile for weight-amortization. Lane = 2 co x (2 rows x 2 cols).
// Weights LDS-staged once (R1's only-working path), read 4xb128+b64 per
// wave-ci (vs R1's 18 b128); x read as 8 float2 (b64, <=2 lanes/bank-pair).
// Per-CU-ci LDS ~850 cyc vs VALU 576 -> conv ~11-14us (was 28 in R1 form,
// 52-55 in all register/scalar weight variants R3-R5).

#define QSCALE (2.5f / 127.f)

__device__ __forceinline__ float quantf(float w) {
  float v = rintf(w * (1.0f / QSCALE));     // round-half-even = jnp.round
  v = fminf(fmaxf(v, -127.f), 127.f);
  return v * QSCALE;
}

// quantize + pack: WQ[(ci*9+tap)*32 + co] = quant(w[co][ci*9+tap])
__global__ __launch_bounds__(256) void quant_k(const float* __restrict__ w1,
                                               const float* __restrict__ w2,
                                               float* __restrict__ q1,
                                               float* __restrict__ q2) {
  int i = blockIdx.x * 256 + threadIdx.x;
  if (i >= 18432) return;
  const float* w = (i < 9216) ? w1 : w2;
  float* dst = (i < 9216) ? q1 : q2;
  int j = (i < 9216) ? i : i - 9216;
  int co = j / 288;
  int r = j - co * 288;                     // r = ci*9 + tap
  dst[r * 32 + co] = quantf(w[j]);
}

// Block: 4 waves. wave wv owns co pair (B+2wv, B+2wv+1). Lane l: cp=l&15
// (cols 2cp,2cp+1), rp=l>>4 (rows h0+2rp, h0+2rp+1). Block tile: 8 rows x
// 32 cols x 8 co. Grid 512 = 32 n x 4 rowgroups x 4 co-groups; 2 blocks/CU.
template <bool AFFINE>
__global__ __launch_bounds__(256, 2) void conv_k(
    const float* __restrict__ in,       // [32][32][32][32] conv input
    const float* __restrict__ wq,       // packed [288][32] this conv
    const float* __restrict__ ps_prev,  // [32][128] prev partial sums (or null)
    const float* __restrict__ pq_prev,  // [32][128] prev partial sumsq
    const float* __restrict__ wq_prev,  // packed prev weights (for wb)
    const float* __restrict__ gprev,    // prev gamma
    const float* __restrict__ bprev,    // prev beta
    float* __restrict__ outb,           // raw conv out
    float* __restrict__ ps_out,         // [32][128]  (idx: co*128 + n*4 + rg)
    float* __restrict__ pq_out) {
  __shared__ __align__(16) float xs[32][10][36];   // 46080 B, rows h0-1..h0+8
  __shared__ __align__(16) float wls[128 * 20];    // 10240 B: [wv*32+ci][20]
  __shared__ float r2a[32][8], r2b[32][8], r2c[32][8];
  __shared__ float abuf[32], bbuf[32];

  const int tid = threadIdx.x;
  const int blk = blockIdx.x;
  const int n = blk >> 4, rg = (blk >> 2) & 3, cg = blk & 3;
  const int h0 = rg << 3, B = cg << 3;

  if (AFFINE) {
    // Redundant per-block BN1 fold: a=g/sqrt(var+eps), b = beta + wb - a*mu.
    const int c = tid & 31, ch = tid >> 5;         // ch 0..7
    float s = 0.f, q = 0.f;
    #pragma unroll
    for (int j = 0; j < 16; ++j) {
      s += ps_prev[c * 128 + ch * 16 + j];
      q += pq_prev[c * 128 + ch * 16 + j];
    }
    float wbp = 0.f;
    #pragma unroll 4
    for (int u = 0; u < 36; ++u) wbp += fabsf(wq_prev[(ch * 36 + u) * 32 + c]);
    r2a[c][ch] = s; r2b[c][ch] = q; r2c[c][ch] = wbp;
    __syncthreads();
    if (tid < 32) {
      double S = 0.0, Q = 0.0; float W = 0.f;
      #pragma unroll
      for (int k = 0; k < 8; ++k) {
        S += (double)r2a[tid][k]; Q += (double)r2b[tid][k]; W += r2c[tid][k];
      }
      const double M = 32768.0;
      const double mu = S / M;
      const double var = Q / M - mu * mu;
      const double inv = 1.0 / sqrt(var + 1e-5);
      const double g = (double)gprev[tid];
      abuf[tid] = (float)(g * inv);
      bbuf[tid] = (float)((double)bprev[tid] + (double)(W * (1.f / 288.f)) - g * inv * mu);
    }
    __syncthreads();
  }

  // ---- stage weights: wls[(wv*32+ci)*20 + tap*2 + j] = wq[..][B+2wv+j]
  for (int i = tid; i < 2560; i += 256) {
    const int t = i >> 7;            // 0..19
    const int pc = i & 127;          // wv*32 + ci
    float v = 0.f;
    if (t < 18) {
      const int tap = t >> 1, j = t & 1;
      const int ci = pc & 31, wv2 = pc >> 5;
      v = wq[(ci * 9 + tap) * 32 + B + 2 * wv2 + j];
    }
    wls[pc * 20 + t] = v;
  }
  // ---- stage x tile (rows h0-1..h0+8, col idx j = global col j-1), padded.
  // pow-2 decode: pair = r*32 + ci; cols by lane32 (coalesced).
  {
    const int lane32 = tid & 31, phase = tid >> 5;
    for (int pair = phase; pair < 320; pair += 8) {
      const int ci = pair & 31, r = pair >> 5;
      const int h = h0 - 1 + r;
      const int rowbase = ((n * 32 + ci) * 32 + h) * 32;
      {
        const int wcol = lane32 - 1;
        float v = 0.f;
        if ((unsigned)h < 32u && (unsigned)wcol < 32u) {
          v = in[rowbase + wcol];
          if (AFFINE) v = fmaxf(fmaf(abuf[ci], v, bbuf[ci]), 0.f);
        }
        xs[ci][r][lane32] = v;
      }
      if (lane32 < 2) {
        const int c2 = 32 + lane32, wcol = c2 - 1;
        float v = 0.f;
        if ((unsigned)h < 32u && (unsigned)wcol < 32u) {
          v = in[rowbase + wcol];
          if (AFFINE) v = fmaxf(fmaf(abuf[ci], v, bbuf[ci]), 0.f);
        }
        xs[ci][r][c2] = v;
      }
    }
  }
  __syncthreads();

  const int l = tid & 63, wv = tid >> 6;
  const int cp = l & 15, rp = l >> 4;

  float acc[2][2][2] = {{{0.f, 0.f}, {0.f, 0.f}}, {{0.f, 0.f}, {0.f, 0.f}}};
  const float* wbase = &wls[wv * 32 * 20];

  #pragma unroll 2
  for (int ci = 0; ci < 32; ++ci) {
    // x window: tile rows 2rp..2rp+3, col idx 2cp..2cp+3 (8 x b64 reads)
    float xv[4][4];
    #pragma unroll
    for (int r4 = 0; r4 < 4; ++r4) {
      const float2 lo = *(const float2*)&xs[ci][2 * rp + r4][2 * cp];
      const float2 hi = *(const float2*)&xs[ci][2 * rp + r4][2 * cp + 2];
      xv[r4][0] = lo.x; xv[r4][1] = lo.y; xv[r4][2] = hi.x; xv[r4][3] = hi.y;
    }
    // weights: 18 floats for this (wave, ci): 4 b128 + 1 b64 (broadcast)
    const float* wp = wbase + ci * 20;
    const float4 W0 = *(const float4*)(wp);
    const float4 W1 = *(const float4*)(wp + 4);
    const float4 W2 = *(const float4*)(wp + 8);
    const float4 W3 = *(const float4*)(wp + 12);
    const float2 W4 = *(const float2*)(wp + 16);
    const float wa[9] = {W0.x, W0.z, W1.x, W1.z, W2.x, W2.z, W3.x, W3.z, W4.x};
    const float wb[9] = {W0.y, W0.w, W1.y, W1.w, W2.y, W2.w, W3.y, W3.w, W4.y};
    #pragma unroll
    for (int kh = 0; kh < 3; ++kh) {
      #pragma unroll
      for (int kw = 0; kw < 3; ++kw) {
        const int t = kh * 3 + kw;
        const float a0 = wa[t], b0 = wb[t];
        #pragma unroll
        for (int dr = 0; dr < 2; ++dr) {
          #pragma unroll
          for (int dc = 0; dc < 2; ++dc) {
            const float x = xv[dr + kh][dc + kw];
            acc[0][dr][dc] += fabsf(x - a0);
            acc[1][dr][dc] += fabsf(x - b0);
          }
        }
      }
    }
  }

  // ---- epilogue: coalesced float2 stores + wave-reduce stats
  #pragma unroll
  for (int p = 0; p < 2; ++p) {
    const int co = B + 2 * wv + p;
    float s = 0.f, q = 0.f;
    #pragma unroll
    for (int dr = 0; dr < 2; ++dr) {
      float2 o2v;
      o2v.x = -acc[p][dr][0];
      o2v.y = -acc[p][dr][1];
      const int h = h0 + 2 * rp + dr;
      *(float2*)&outb[((n * 32 + co) * 32 + h) * 32 + 2 * cp] = o2v;
      s += o2v.x + o2v.y;
      q += o2v.x * o2v.x + o2v.y * o2v.y;
    }
    #pragma unroll
    for (int d = 32; d; d >>= 1) { s += __shfl_xor(s, d); q += __shfl_xor(q, d); }
    if (l == 0) {
      ps_out[co * 128 + n * 4 + rg] = s;
      pq_out[co * 128 + n * 4 + rg] = q;
    }
  }
}

// ---- K3: redundant BN2 fold + relu(a2*o2 + b2 + x) ----
__global__ __launch_bounds__(256) void final_k(
    const float* __restrict__ o2, const float* __restrict__ xres,
    const float* __restrict__ ps, const float* __restrict__ pq,
    const float* __restrict__ wq2, const float* __restrict__ g2,
    const float* __restrict__ b2, float* __restrict__ out) {
  __shared__ float r2a[32][8], r2b[32][8], r2c[32][8];
  __shared__ float abuf[32], bbuf[32];
  const int tid = threadIdx.x;
  const int c = tid & 31, ch = tid >> 5;
  float s = 0.f, q = 0.f;
  #pragma unroll
  for (int j = 0; j < 16; ++j) {
    s += ps[c * 128 + ch * 16 + j];
    q += pq[c * 128 + ch * 16 + j];
  }
  float wbp = 0.f;
  #pragma unroll 4
  for (int u = 0; u < 36; ++u) wbp += fabsf(wq2[(ch * 36 + u) * 32 + c]);
  r2a[c][ch] = s; r2b[c][ch] = q; r2c[c][ch] = wbp;
  __syncthreads();
  if (tid < 32) {
    double S = 0.0, Q = 0.0; float W = 0.f;
    #pragma unroll
    for (int k = 0; k < 8; ++k) {
      S += (double)r2a[tid][k]; Q += (double)r2b[tid][k]; W += r2c[tid][k];
    }
    const double M = 32768.0;
    const double mu = S / M;
    const double var = Q / M - mu * mu;
    const double inv = 1.0 / sqrt(var + 1e-5);
    const double g = (double)g2[tid];
    abuf[tid] = (float)(g * inv);
    bbuf[tid] = (float)((double)b2[tid] + (double)(W * (1.f / 288.f)) - g * inv * mu);
  }
  __syncthreads();

  const int base = blockIdx.x * 512;  // float4 units; 512 x 512 = 262144
  for (int i = tid; i < 512; i += 256) {
    const int f4 = base + i;
    const int cc = (f4 >> 8) & 31;
    const float4 o = ((const float4*)o2)[f4];
    const float4 xr = ((const float4*)xres)[f4];
    const float av = abuf[cc], bv = bbuf[cc];
    float4 r;
    r.x = fmaxf(fmaf(av, o.x, bv) + xr.x, 0.f);
    r.y = fmaxf(fmaf(av, o.y, bv) + xr.y, 0.f);
    r.z = fmaxf(fmaf(av, o.z, bv) + xr.z, 0.f);
    r.w = fmaxf(fmaf(av, o.w, bv) + xr.w, 0.f);
    ((float4*)out)[f4] = r;
  }
}

extern "C" void kernel_launch(void* const* d_in, const int* in_sizes, int n_in,
                              void* d_out, int out_size, void* d_ws, size_t ws_size,
                              hipStream_t stream) {
  const float* x   = (const float*)d_in[0];
  const float* w1  = (const float*)d_in[1];
  const float* g1  = (const float*)d_in[2];
  const float* be1 = (const float*)d_in[3];
  const float* w2  = (const float*)d_in[4];
  const float* g2  = (const float*)d_in[5];
  const float* be2 = (const float*)d_in[6];
  float* ws = (float*)d_ws;

  float* WQ1 = ws;                  // 9216  (packed [288][32])
  float* WQ2 = ws + 9216;           // 9216
  float* PS1 = ws + 18432;          // [32][128] = 4096
  float* PQ1 = ws + 22528;          // 4096
  float* PS2 = ws + 26624;          // 4096
  float* PQ2 = ws + 30720;          // 4096
  float* O1  = ws + 34816;          // 1048576 (16B aligned)
  float* O2  = O1 + 1048576;        // 1048576
  float* out = (float*)d_out;

  quant_k<<<72, 256, 0, stream>>>(w1, w2, WQ1, WQ2);
  conv_k<false><<<512, 256, 0, stream>>>(x, WQ1, nullptr, nullptr, nullptr,
                                         nullptr, nullptr, O1, PS1, PQ1);
  conv_k<true><<<512, 256, 0, stream>>>(O1, WQ2, PS1, PQ1, WQ1, g1, be1,
                                        O2, PS2, PQ2);
  final_k<<<512, 256, 0, stream>>>(O2, x, PS2, PQ2, WQ2, g2, be2, out);
}